// Round 2
// baseline (1020.334 us; speedup 1.0000x reference)
//
#include <hip/hip_runtime.h>
#include <hip/hip_bf16.h>

#define HH 96
#define WW 160
#define BATCH 8
#define NPIX (BATCH*HH*WW)   // 122880
#define CIN 256

typedef short bf16x8 __attribute__((ext_vector_type(8)));
typedef float f32x4 __attribute__((ext_vector_type(4)));

__device__ __forceinline__ unsigned short f2bf(float f) {
    unsigned int u = __float_as_uint(f);
    u = (u + 0x7fffu + ((u >> 16) & 1u)) >> 16;   // RNE
    return (unsigned short)u;
}

__device__ __forceinline__ void gload16(const void* g, void* l) {
    __builtin_amdgcn_global_load_lds(
        (const __attribute__((address_space(1))) void*)g,
        (__attribute__((address_space(3))) void*)l,
        16, 0, 0);
}

// ---------------- prep: BN fold + zero page ----------------
__global__ __launch_bounds__(256) void prep_scalars(
    const float* __restrict__ b1, const float* __restrict__ g1, const float* __restrict__ be1,
    const float* __restrict__ m1, const float* __restrict__ v1,
    const float* __restrict__ b2, const float* __restrict__ g2, const float* __restrict__ be2,
    const float* __restrict__ m2, const float* __restrict__ v2,
    const float* __restrict__ ub1,
    float* __restrict__ scale1, float* __restrict__ bias1,
    float* __restrict__ scale2, float* __restrict__ bias2,
    float* __restrict__ uscale, float* __restrict__ ubias,
    unsigned short* __restrict__ zp)
{
    int t = threadIdx.x;
    float s1 = g1[t] * rsqrtf(v1[t] + 1e-5f);
    scale1[t] = s1;
    bias1[t]  = (b1[t] - m1[t]) * s1 + be1[t];
    float s2 = g2[t] * rsqrtf(v2[t] + 1e-5f);
    scale2[t] = s2;
    bias2[t]  = (b2[t] - m2[t]) * s2 + be2[t];
    if (t < 128) { uscale[t] = 1.0f; ubias[t] = ub1[t]; zp[t] = 0; }
}

// ---------------- prep: pack weights OIHW f32 -> [cout][pos][cin] bf16 ----------------
__global__ __launch_bounds__(256) void prep_weights(
    const float* __restrict__ w1, const float* __restrict__ w2, const float* __restrict__ uw1,
    unsigned short* __restrict__ w1T, unsigned short* __restrict__ w2T, unsigned short* __restrict__ uw1T)
{
    const int S = 256 * 2304;       // 589824
    int i = blockIdx.x * 256 + threadIdx.x;
    if (i < S) {
        int co = i / 2304, r = i % 2304, pos = r >> 8, ci = r & 255;
        w1T[i] = f2bf(w1[(co * 256 + ci) * 9 + pos]);
    } else if (i < 2 * S) {
        int j = i - S;
        int co = j / 2304, r = j % 2304, pos = r >> 8, ci = r & 255;
        w2T[j] = f2bf(w2[(co * 256 + ci) * 9 + pos]);
    } else {
        int j = i - 2 * S;          // < 128*2304
        int co = j / 2304, r = j % 2304, pos = r >> 8, ci = r & 255;
        uw1T[j] = f2bf(uw1[(co * 256 + ci) * 9 + pos]);
    }
}

// ---------------- prep: NCHW f32 -> NHWC bf16 transpose ----------------
__global__ __launch_bounds__(256) void pack_features(
    const float* __restrict__ f, unsigned short* __restrict__ ft)
{
    __shared__ float tile[32][33];
    int x0 = blockIdx.x * 32;       // W/32 = 5
    int c0 = blockIdx.y * 32;       // C/32 = 8
    int by = blockIdx.z;            // B*H = 768
    int b = by / HH, y = by % HH;
    int tx = threadIdx.x & 31, tg = threadIdx.x >> 5;   // tg 0..7
    const float* src = f + (((size_t)(b * CIN + c0) * HH + y) * WW) + x0;
    #pragma unroll
    for (int i = 0; i < 4; ++i) {
        int cl = tg + i * 8;
        tile[cl][tx] = src[(size_t)cl * HH * WW + tx];
    }
    __syncthreads();
    size_t nbase = ((size_t)b * HH + y) * WW + x0;
    #pragma unroll
    for (int i = 0; i < 4; ++i) {
        int xl = tg + i * 8;
        ft[(nbase + xl) * CIN + c0 + tx] = f2bf(tile[tx][xl]);
    }
}

// ---------------- 3x3 conv as implicit GEMM, bf16 MFMA 16x16x32, 128x128 tile ----------------
// LDS physical layout per wave-slot (1024B = 16 rows x 4 k-quarters):
//   granule l  <->  (row_low = l&15, kq = l>>4)
// so fragment reads (fixed kq, rows 0..15 across lanes) hit 64 consecutive
// granules -> conflict-free (was: row-major, 4-8 way conflicts, 1.77e7/dispatch).
__global__ __launch_bounds__(256) void conv3x3_mfma(
    const unsigned short* __restrict__ in_t,
    const unsigned short* __restrict__ wT,
    const float* __restrict__ scale, const float* __restrict__ bias,
    unsigned short* __restrict__ out_t,
    const unsigned short* __restrict__ zp,
    int Cout)
{
    __shared__ unsigned short Alds[128 * 32];   // 8 KB
    __shared__ unsigned short Blds[128 * 32];   // 8 KB

    const int t = threadIdx.x;
    const int wave = t >> 6;
    const int l = t & 63;
    const int n0 = blockIdx.x * 128;
    const int m0 = blockIdx.y * 128;

    // staging mapping: lane l covers (row_low = l&15, k-quarter = l>>4); two slots of 16 rows
    const int lrow = l & 15;
    const int lkq = l >> 4;
    const int rowS0 = wave * 32 + lrow;          // slot 0
    const int rowS1 = wave * 32 + 16 + lrow;     // slot 1

    const unsigned short* asrc0 = wT + ((size_t)(m0 + rowS0) * 9) * CIN + lkq * 8;
    const unsigned short* asrc1 = wT + ((size_t)(m0 + rowS1) * 9) * CIN + lkq * 8;

    const int nB0 = n0 + rowS0;
    const int nB1 = n0 + rowS1;
    const unsigned short* bsrc0 = in_t + (size_t)nB0 * CIN + lkq * 8;
    const unsigned short* bsrc1 = in_t + (size_t)nB1 * CIN + lkq * 8;
    const int hw0 = nB0 % (HH * WW), py0 = hw0 / WW, px0 = hw0 % WW;
    const int hw1 = nB1 % (HH * WW), py1 = hw1 / WW, px1 = hw1 % WW;

    unsigned short* aldsw = &Alds[wave * 1024];
    unsigned short* bldsw = &Blds[wave * 1024];

    const int wm = wave >> 1, wn = wave & 1;
    const int quad = l >> 4, lane16 = l & 15;

    f32x4 acc[4][4];
    #pragma unroll
    for (int mt = 0; mt < 4; ++mt)
        #pragma unroll
        for (int nt = 0; nt < 4; ++nt)
            acc[mt][nt] = (f32x4){0.f, 0.f, 0.f, 0.f};

    // fragment LDS addresses (ushort index): logical (row, k=quad*8)
    //   = ((row>>4)<<9) + quad*128 + (row&15)*8 ; here row&15 == lane16.
    // A rows: wm*64 + i*16 + lane16  -> slot index wm*4+i
    // B rows: wn*64 + i*16 + lane16  -> slot index wn*4+i

    for (int pos = 0; pos < 9; ++pos) {
        const int dy = pos / 3 - 1, dx = pos % 3 - 1;
        const unsigned short* ap0 = asrc0 + pos * CIN;
        const unsigned short* ap1 = asrc1 + pos * CIN;
        const bool v0 = ((unsigned)(py0 + dy) < HH) && ((unsigned)(px0 + dx) < WW);
        const bool v1 = ((unsigned)(py1 + dy) < HH) && ((unsigned)(px1 + dx) < WW);
        const unsigned short* bp0 = bsrc0 + (dy * WW + dx) * CIN;
        const unsigned short* bp1 = bsrc1 + (dy * WW + dx) * CIN;
        for (int cc = 0; cc < 8; ++cc) {
            const int c0 = cc * 32;
            __syncthreads();    // previous tiles fully consumed
            gload16(ap0 + c0, aldsw);
            gload16(ap1 + c0, aldsw + 512);
            gload16(v0 ? (bp0 + c0) : zp, bldsw);
            gload16(v1 ? (bp1 + c0) : zp, bldsw + 512);
            __syncthreads();    // drains vmcnt before barrier -> tiles visible

            bf16x8 af[4], bfr[4];
            #pragma unroll
            for (int i = 0; i < 4; ++i)
                af[i] = *(const bf16x8*)&Alds[((wm * 4 + i) << 9) + quad * 128 + lane16 * 8];
            #pragma unroll
            for (int i = 0; i < 4; ++i)
                bfr[i] = *(const bf16x8*)&Blds[((wn * 4 + i) << 9) + quad * 128 + lane16 * 8];
            #pragma unroll
            for (int mt = 0; mt < 4; ++mt)
                #pragma unroll
                for (int nt = 0; nt < 4; ++nt)
                    acc[mt][nt] = __builtin_amdgcn_mfma_f32_16x16x32_bf16(
                        af[mt], bfr[nt], acc[mt][nt], 0, 0, 0);
        }
    }

    // epilogue: y = relu(acc*scale + bias) -> bf16 NHWC
    #pragma unroll
    for (int mt = 0; mt < 4; ++mt) {
        const int mg = m0 + wm * 64 + mt * 16 + quad * 4;
        const float4 sc = *(const float4*)&scale[mg];
        const float4 bi = *(const float4*)&bias[mg];
        #pragma unroll
        for (int nt = 0; nt < 4; ++nt) {
            const int n = n0 + wn * 64 + nt * 16 + lane16;
            ushort4 pk;
            pk.x = f2bf(fmaxf(acc[mt][nt][0] * sc.x + bi.x, 0.f));
            pk.y = f2bf(fmaxf(acc[mt][nt][1] * sc.y + bi.y, 0.f));
            pk.z = f2bf(fmaxf(acc[mt][nt][2] * sc.z + bi.z, 0.f));
            pk.w = f2bf(fmaxf(acc[mt][nt][3] * sc.w + bi.w, 0.f));
            *(ushort4*)&out_t[(size_t)n * Cout + mg] = pk;
        }
    }
}

// ---------------- depth head: 1x1 conv over 256ch + sigmoid + depth transform ----------------
__global__ __launch_bounds__(256) void head_depth(
    const unsigned short* __restrict__ h2, const float* __restrict__ w3,
    const float* __restrict__ b3, float* __restrict__ out)
{
    __shared__ float ws[256];
    ws[threadIdx.x] = w3[threadIdx.x];
    __syncthreads();
    const int pix = blockIdx.x * 64 + (threadIdx.x >> 2);
    const int q = threadIdx.x & 3;
    const unsigned short* p = h2 + (size_t)pix * 256 + q * 64;
    float s = 0.f;
    #pragma unroll
    for (int i = 0; i < 64; i += 8) {
        uint4 v = *(const uint4*)(p + i);
        const float* wq = &ws[q * 64 + i];
        s += __uint_as_float(v.x << 16) * wq[0];
        s += __uint_as_float(v.x & 0xffff0000u) * wq[1];
        s += __uint_as_float(v.y << 16) * wq[2];
        s += __uint_as_float(v.y & 0xffff0000u) * wq[3];
        s += __uint_as_float(v.z << 16) * wq[4];
        s += __uint_as_float(v.z & 0xffff0000u) * wq[5];
        s += __uint_as_float(v.w << 16) * wq[6];
        s += __uint_as_float(v.w & 0xffff0000u) * wq[7];
    }
    s += __shfl_xor(s, 1);
    s += __shfl_xor(s, 2);
    if (q == 0) {
        float x = s + b3[0];
        float sig = 1.f / (1.f + expf(-x));
        out[pix] = 1.f / (0.01f + 9.99f * sig);   // 1/(min_disp + (max-min)*disp)
    }
}

// ---------------- uncertainty head: 1x1 conv over 128ch + softplus ----------------
__global__ __launch_bounds__(256) void head_unc(
    const unsigned short* __restrict__ u, const float* __restrict__ uw2,
    const float* __restrict__ ub2, float* __restrict__ out)
{
    __shared__ float ws[128];
    if (threadIdx.x < 128) ws[threadIdx.x] = uw2[threadIdx.x];
    __syncthreads();
    const int pix = blockIdx.x * 64 + (threadIdx.x >> 2);
    const int q = threadIdx.x & 3;
    const unsigned short* p = u + (size_t)pix * 128 + q * 32;
    float s = 0.f;
    #pragma unroll
    for (int i = 0; i < 32; i += 8) {
        uint4 v = *(const uint4*)(p + i);
        const float* wq = &ws[q * 32 + i];
        s += __uint_as_float(v.x << 16) * wq[0];
        s += __uint_as_float(v.x & 0xffff0000u) * wq[1];
        s += __uint_as_float(v.y << 16) * wq[2];
        s += __uint_as_float(v.y & 0xffff0000u) * wq[3];
        s += __uint_as_float(v.z << 16) * wq[4];
        s += __uint_as_float(v.z & 0xffff0000u) * wq[5];
        s += __uint_as_float(v.w << 16) * wq[6];
        s += __uint_as_float(v.w & 0xffff0000u) * wq[7];
    }
    s += __shfl_xor(s, 1);
    s += __shfl_xor(s, 2);
    if (q == 0) {
        float x = s + ub2[0];
        out[pix] = fmaxf(x, 0.f) + log1pf(expf(-fabsf(x)));
    }
}

// ---------------- per-box lower-median via 4-pass radix select on float bits ----------------
__global__ __launch_bounds__(256) void median_kernel(
    const float* __restrict__ depth, const int* __restrict__ bboxes, float* __restrict__ obj)
{
    const int bi = blockIdx.x;          // b*64 + box
    const int b = bi >> 6;
    const int* bb = bboxes + (size_t)bi * 4;
    int x1 = max(bb[0], 0), y1 = max(bb[1], 0);
    int x2 = min(bb[2], WW), y2 = min(bb[3], HH);
    int w = x2 - x1, h = y2 - y1;
    if (w <= 0 || h <= 0) {
        if (threadIdx.x == 0) obj[bi] = 0.f;
        return;
    }
    const int wh = w * h;
    int tgt = (wh - 1) >> 1;            // lower median index
    const float* dbase = depth + (size_t)b * HH * WW;

    __shared__ unsigned int hist[256];
    __shared__ unsigned int sel_prefix, sel_target;
    unsigned int prefix = 0;

    for (int pass = 0; pass < 4; ++pass) {
        const int shift = 24 - 8 * pass;
        hist[threadIdx.x] = 0;
        __syncthreads();
        const unsigned int mask_high = (pass == 0) ? 0u : (0xFFFFFFFFu << (shift + 8));
        for (int idx = threadIdx.x; idx < wh; idx += 256) {
            int yy = y1 + idx / w, xx = x1 + idx % w;
            unsigned int uu = __float_as_uint(dbase[yy * WW + xx]);
            if ((uu & mask_high) == (prefix & mask_high))
                atomicAdd(&hist[(uu >> shift) & 255], 1u);
        }
        __syncthreads();
        if (threadIdx.x == 0) {
            unsigned int cum = 0;
            for (int bin = 0; bin < 256; ++bin) {
                unsigned int c = hist[bin];
                if (cum + c > (unsigned int)tgt) {
                    sel_target = (unsigned int)tgt - cum;
                    sel_prefix = prefix | ((unsigned int)bin << shift);
                    break;
                }
                cum += c;
            }
        }
        __syncthreads();
        prefix = sel_prefix;
        tgt = (int)sel_target;
    }
    if (threadIdx.x == 0) obj[bi] = __uint_as_float(prefix);
}

extern "C" void kernel_launch(void* const* d_in, const int* in_sizes, int n_in,
                              void* d_out, int out_size, void* d_ws, size_t ws_size,
                              hipStream_t stream) {
    const float* features = (const float*)d_in[0];
    const int*   bboxes   = (const int*)d_in[1];
    const float* w1  = (const float*)d_in[2];
    const float* b1  = (const float*)d_in[3];
    const float* g1  = (const float*)d_in[4];
    const float* be1 = (const float*)d_in[5];
    const float* m1  = (const float*)d_in[6];
    const float* v1  = (const float*)d_in[7];
    const float* w2  = (const float*)d_in[8];
    const float* b2  = (const float*)d_in[9];
    const float* g2  = (const float*)d_in[10];
    const float* be2 = (const float*)d_in[11];
    const float* m2  = (const float*)d_in[12];
    const float* v2  = (const float*)d_in[13];
    const float* w3  = (const float*)d_in[14];
    const float* b3  = (const float*)d_in[15];
    const float* uw1 = (const float*)d_in[16];
    const float* ub1 = (const float*)d_in[17];
    const float* uw2 = (const float*)d_in[18];
    const float* ub2 = (const float*)d_in[19];
    float* out = (float*)d_out;

    char* ws = (char*)d_ws;
    unsigned short* feat_t = (unsigned short*)(ws);                 // 62,914,560  (reused as h2_t)
    unsigned short* h1_t   = (unsigned short*)(ws + 62914560);      // 62,914,560
    unsigned short* u_t    = (unsigned short*)(ws + 125829120);     // 31,457,280
    unsigned short* w1T    = (unsigned short*)(ws + 157286400);     // 1,179,648
    unsigned short* w2T    = w1T + 589824;                          // 1,179,648
    unsigned short* uw1T   = w2T + 589824;                          //   589,824
    float* scale1 = (float*)(uw1T + 294912);
    float* bias1  = scale1 + 256;
    float* scale2 = bias1 + 256;
    float* bias2  = scale2 + 256;
    float* uscale = bias2 + 256;
    float* ubias  = uscale + 128;
    unsigned short* zp = (unsigned short*)(ubias + 128);            // 256 B zero page

    prep_scalars<<<1, 256, 0, stream>>>(b1, g1, be1, m1, v1, b2, g2, be2, m2, v2, ub1,
                                        scale1, bias1, scale2, bias2, uscale, ubias, zp);
    prep_weights<<<5760, 256, 0, stream>>>(w1, w2, uw1, w1T, w2T, uw1T);
    pack_features<<<dim3(WW / 32, CIN / 32, BATCH * HH), 256, 0, stream>>>(features, feat_t);

    conv3x3_mfma<<<dim3(NPIX / 128, 2), 256, 0, stream>>>(feat_t, w1T, scale1, bias1, h1_t, zp, 256);
    conv3x3_mfma<<<dim3(NPIX / 128, 1), 256, 0, stream>>>(feat_t, uw1T, uscale, ubias, u_t, zp, 128);
    unsigned short* h2_t = feat_t;
    conv3x3_mfma<<<dim3(NPIX / 128, 2), 256, 0, stream>>>(h1_t, w2T, scale2, bias2, h2_t, zp, 256);

    head_depth<<<NPIX / 64, 256, 0, stream>>>(h2_t, w3, b3, out);
    head_unc<<<NPIX / 64, 256, 0, stream>>>(u_t, uw2, ub2, out + NPIX);
    median_kernel<<<BATCH * 64, 256, 0, stream>>>(out, bboxes, out + 2 * NPIX);
}

// Round 3
// 799.126 us; speedup vs baseline: 1.2768x; 1.2768x over previous
//
#include <hip/hip_runtime.h>
#include <hip/hip_bf16.h>

#define HH 96
#define WW 160
#define BATCH 8
#define NPIX (BATCH*HH*WW)   // 122880
#define CIN 256

typedef short bf16x8 __attribute__((ext_vector_type(8)));
typedef float f32x4 __attribute__((ext_vector_type(4)));

__device__ __forceinline__ unsigned short f2bf(float f) {
    unsigned int u = __float_as_uint(f);
    u = (u + 0x7fffu + ((u >> 16) & 1u)) >> 16;   // RNE
    return (unsigned short)u;
}

__device__ __forceinline__ void gload16(const void* g, void* l) {
    __builtin_amdgcn_global_load_lds(
        (const __attribute__((address_space(1))) void*)g,
        (__attribute__((address_space(3))) void*)l,
        16, 0, 0);
}

// ---------------- prep: BN fold + zero page ----------------
__global__ __launch_bounds__(256) void prep_scalars(
    const float* __restrict__ b1, const float* __restrict__ g1, const float* __restrict__ be1,
    const float* __restrict__ m1, const float* __restrict__ v1,
    const float* __restrict__ b2, const float* __restrict__ g2, const float* __restrict__ be2,
    const float* __restrict__ m2, const float* __restrict__ v2,
    const float* __restrict__ ub1,
    float* __restrict__ scale1, float* __restrict__ bias1,
    float* __restrict__ scale2, float* __restrict__ bias2,
    float* __restrict__ uscale, float* __restrict__ ubias,
    unsigned short* __restrict__ zp)
{
    int t = threadIdx.x;
    float s1 = g1[t] * rsqrtf(v1[t] + 1e-5f);
    scale1[t] = s1;
    bias1[t]  = (b1[t] - m1[t]) * s1 + be1[t];
    float s2 = g2[t] * rsqrtf(v2[t] + 1e-5f);
    scale2[t] = s2;
    bias2[t]  = (b2[t] - m2[t]) * s2 + be2[t];
    if (t < 128) { uscale[t] = 1.0f; ubias[t] = ub1[t]; zp[t] = 0; }
}

// ---------------- prep: pack weights OIHW f32 -> [cout][pos][cin] bf16 ----------------
__global__ __launch_bounds__(256) void prep_weights(
    const float* __restrict__ w1, const float* __restrict__ w2, const float* __restrict__ uw1,
    unsigned short* __restrict__ w1T, unsigned short* __restrict__ w2T, unsigned short* __restrict__ uw1T)
{
    const int S = 256 * 2304;       // 589824
    int i = blockIdx.x * 256 + threadIdx.x;
    if (i < S) {
        int co = i / 2304, r = i % 2304, pos = r >> 8, ci = r & 255;
        w1T[i] = f2bf(w1[(co * 256 + ci) * 9 + pos]);
    } else if (i < 2 * S) {
        int j = i - S;
        int co = j / 2304, r = j % 2304, pos = r >> 8, ci = r & 255;
        w2T[j] = f2bf(w2[(co * 256 + ci) * 9 + pos]);
    } else {
        int j = i - 2 * S;          // < 128*2304
        int co = j / 2304, r = j % 2304, pos = r >> 8, ci = r & 255;
        uw1T[j] = f2bf(uw1[(co * 256 + ci) * 9 + pos]);
    }
}

// ---------------- prep: NCHW f32 -> NHWC bf16 transpose ----------------
__global__ __launch_bounds__(256) void pack_features(
    const float* __restrict__ f, unsigned short* __restrict__ ft)
{
    __shared__ float tile[32][33];
    int x0 = blockIdx.x * 32;       // W/32 = 5
    int c0 = blockIdx.y * 32;       // C/32 = 8
    int by = blockIdx.z;            // B*H = 768
    int b = by / HH, y = by % HH;
    int tx = threadIdx.x & 31, tg = threadIdx.x >> 5;   // tg 0..7
    const float* src = f + (((size_t)(b * CIN + c0) * HH + y) * WW) + x0;
    #pragma unroll
    for (int i = 0; i < 4; ++i) {
        int cl = tg + i * 8;
        tile[cl][tx] = src[(size_t)cl * HH * WW + tx];
    }
    __syncthreads();
    size_t nbase = ((size_t)b * HH + y) * WW + x0;
    #pragma unroll
    for (int i = 0; i < 4; ++i) {
        int xl = tg + i * 8;
        ft[(nbase + xl) * CIN + c0 + tx] = f2bf(tile[tx][xl]);
    }
}

// ---------------- 3x3 conv as implicit GEMM, bf16 MFMA 16x16x32, 128x128 tile ----------------
// Staging (global_load_lds, LDS dest pinned to base+lane*16):
//   lane l fetches row (l>>2), k-quarter ((l&3) ^ ((l>>3)&3)).
//   - global side: lanes 0-3 cover ONE contiguous 64B line (permuted within) -> full
//     coalescing (round-2 regression was 512B-strided lanes: 64 scattered 16B reqs).
//   - LDS side: physical granule p=4r+(q^((r>>1)&3)); fragment read at fixed quad over
//     rows 0..15 hits bank-groups 4(r&1)+(quad^((r>>1)&3)) = all 8 groups x2 -> 2-way = free.
__global__ __launch_bounds__(256) void conv3x3_mfma(
    const unsigned short* __restrict__ in_t,
    const unsigned short* __restrict__ wT,
    const float* __restrict__ scale, const float* __restrict__ bias,
    unsigned short* __restrict__ out_t,
    const unsigned short* __restrict__ zp,
    int Cout)
{
    __shared__ unsigned short Alds[128 * 32];   // 8 KB
    __shared__ unsigned short Blds[128 * 32];   // 8 KB

    const int t = threadIdx.x;
    const int wave = t >> 6;
    const int l = t & 63;
    const int n0 = blockIdx.x * 128;
    const int m0 = blockIdx.y * 128;

    // staging: lane l -> (row = l>>2, swizzled quarter)
    const int lrow = l >> 2;
    const int lkq = (l & 3) ^ ((l >> 3) & 3);
    const int rowS0 = wave * 32 + lrow;          // slot 0
    const int rowS1 = wave * 32 + 16 + lrow;     // slot 1

    const unsigned short* asrc0 = wT + ((size_t)(m0 + rowS0) * 9) * CIN + lkq * 8;
    const unsigned short* asrc1 = wT + ((size_t)(m0 + rowS1) * 9) * CIN + lkq * 8;

    const int nB0 = n0 + rowS0;
    const int nB1 = n0 + rowS1;
    const unsigned short* bsrc0 = in_t + (size_t)nB0 * CIN + lkq * 8;
    const unsigned short* bsrc1 = in_t + (size_t)nB1 * CIN + lkq * 8;
    const int hw0 = nB0 % (HH * WW), py0 = hw0 / WW, px0 = hw0 % WW;
    const int hw1 = nB1 % (HH * WW), py1 = hw1 / WW, px1 = hw1 % WW;

    unsigned short* aldsw = &Alds[wave * 1024];
    unsigned short* bldsw = &Blds[wave * 1024];

    const int wm = wave >> 1, wn = wave & 1;
    const int quad = l >> 4, lane16 = l & 15;

    f32x4 acc[4][4];
    #pragma unroll
    for (int mt = 0; mt < 4; ++mt)
        #pragma unroll
        for (int nt = 0; nt < 4; ++nt)
            acc[mt][nt] = (f32x4){0.f, 0.f, 0.f, 0.f};

    // fragment LDS address (ushorts): slot*512 + row*32 + ((quad ^ ((row>>1)&3)) * 8)
    const int fragoff = lane16 * 32 + ((quad ^ ((lane16 >> 1) & 3)) << 3);

    for (int pos = 0; pos < 9; ++pos) {
        const int dy = pos / 3 - 1, dx = pos % 3 - 1;
        const unsigned short* ap0 = asrc0 + pos * CIN;
        const unsigned short* ap1 = asrc1 + pos * CIN;
        const bool v0 = ((unsigned)(py0 + dy) < HH) && ((unsigned)(px0 + dx) < WW);
        const bool v1 = ((unsigned)(py1 + dy) < HH) && ((unsigned)(px1 + dx) < WW);
        const unsigned short* bp0 = bsrc0 + (dy * WW + dx) * CIN;
        const unsigned short* bp1 = bsrc1 + (dy * WW + dx) * CIN;
        for (int cc = 0; cc < 8; ++cc) {
            const int c0 = cc * 32;
            __syncthreads();    // previous tiles fully consumed
            gload16(ap0 + c0, aldsw);
            gload16(ap1 + c0, aldsw + 512);
            gload16(v0 ? (bp0 + c0) : zp, bldsw);
            gload16(v1 ? (bp1 + c0) : zp, bldsw + 512);
            __syncthreads();    // drains vmcnt before barrier -> tiles visible

            bf16x8 af[4], bfr[4];
            #pragma unroll
            for (int i = 0; i < 4; ++i)
                af[i] = *(const bf16x8*)&Alds[((wm * 4 + i) << 9) + fragoff];
            #pragma unroll
            for (int i = 0; i < 4; ++i)
                bfr[i] = *(const bf16x8*)&Blds[((wn * 4 + i) << 9) + fragoff];
            #pragma unroll
            for (int mt = 0; mt < 4; ++mt)
                #pragma unroll
                for (int nt = 0; nt < 4; ++nt)
                    acc[mt][nt] = __builtin_amdgcn_mfma_f32_16x16x32_bf16(
                        af[mt], bfr[nt], acc[mt][nt], 0, 0, 0);
        }
    }

    // epilogue: y = relu(acc*scale + bias) -> bf16 NHWC
    #pragma unroll
    for (int mt = 0; mt < 4; ++mt) {
        const int mg = m0 + wm * 64 + mt * 16 + quad * 4;
        const float4 sc = *(const float4*)&scale[mg];
        const float4 bi = *(const float4*)&bias[mg];
        #pragma unroll
        for (int nt = 0; nt < 4; ++nt) {
            const int n = n0 + wn * 64 + nt * 16 + lane16;
            ushort4 pk;
            pk.x = f2bf(fmaxf(acc[mt][nt][0] * sc.x + bi.x, 0.f));
            pk.y = f2bf(fmaxf(acc[mt][nt][1] * sc.y + bi.y, 0.f));
            pk.z = f2bf(fmaxf(acc[mt][nt][2] * sc.z + bi.z, 0.f));
            pk.w = f2bf(fmaxf(acc[mt][nt][3] * sc.w + bi.w, 0.f));
            *(ushort4*)&out_t[(size_t)n * Cout + mg] = pk;
        }
    }
}

// ---------------- depth head: 1x1 conv over 256ch + sigmoid + depth transform ----------------
__global__ __launch_bounds__(256) void head_depth(
    const unsigned short* __restrict__ h2, const float* __restrict__ w3,
    const float* __restrict__ b3, float* __restrict__ out)
{
    __shared__ float ws[256];
    ws[threadIdx.x] = w3[threadIdx.x];
    __syncthreads();
    const int pix = blockIdx.x * 64 + (threadIdx.x >> 2);
    const int q = threadIdx.x & 3;
    const unsigned short* p = h2 + (size_t)pix * 256 + q * 64;
    float s = 0.f;
    #pragma unroll
    for (int i = 0; i < 64; i += 8) {
        uint4 v = *(const uint4*)(p + i);
        const float* wq = &ws[q * 64 + i];
        s += __uint_as_float(v.x << 16) * wq[0];
        s += __uint_as_float(v.x & 0xffff0000u) * wq[1];
        s += __uint_as_float(v.y << 16) * wq[2];
        s += __uint_as_float(v.y & 0xffff0000u) * wq[3];
        s += __uint_as_float(v.z << 16) * wq[4];
        s += __uint_as_float(v.z & 0xffff0000u) * wq[5];
        s += __uint_as_float(v.w << 16) * wq[6];
        s += __uint_as_float(v.w & 0xffff0000u) * wq[7];
    }
    s += __shfl_xor(s, 1);
    s += __shfl_xor(s, 2);
    if (q == 0) {
        float x = s + b3[0];
        float sig = 1.f / (1.f + expf(-x));
        out[pix] = 1.f / (0.01f + 9.99f * sig);   // 1/(min_disp + (max-min)*disp)
    }
}

// ---------------- uncertainty head: 1x1 conv over 128ch + softplus ----------------
__global__ __launch_bounds__(256) void head_unc(
    const unsigned short* __restrict__ u, const float* __restrict__ uw2,
    const float* __restrict__ ub2, float* __restrict__ out)
{
    __shared__ float ws[128];
    if (threadIdx.x < 128) ws[threadIdx.x] = uw2[threadIdx.x];
    __syncthreads();
    const int pix = blockIdx.x * 64 + (threadIdx.x >> 2);
    const int q = threadIdx.x & 3;
    const unsigned short* p = u + (size_t)pix * 128 + q * 32;
    float s = 0.f;
    #pragma unroll
    for (int i = 0; i < 32; i += 8) {
        uint4 v = *(const uint4*)(p + i);
        const float* wq = &ws[q * 32 + i];
        s += __uint_as_float(v.x << 16) * wq[0];
        s += __uint_as_float(v.x & 0xffff0000u) * wq[1];
        s += __uint_as_float(v.y << 16) * wq[2];
        s += __uint_as_float(v.y & 0xffff0000u) * wq[3];
        s += __uint_as_float(v.z << 16) * wq[4];
        s += __uint_as_float(v.z & 0xffff0000u) * wq[5];
        s += __uint_as_float(v.w << 16) * wq[6];
        s += __uint_as_float(v.w & 0xffff0000u) * wq[7];
    }
    s += __shfl_xor(s, 1);
    s += __shfl_xor(s, 2);
    if (q == 0) {
        float x = s + ub2[0];
        out[pix] = fmaxf(x, 0.f) + log1pf(expf(-fabsf(x)));
    }
}

// ---------------- per-box lower-median via 4-pass radix select on float bits ----------------
__global__ __launch_bounds__(256) void median_kernel(
    const float* __restrict__ depth, const int* __restrict__ bboxes, float* __restrict__ obj)
{
    const int bi = blockIdx.x;          // b*64 + box
    const int b = bi >> 6;
    const int* bb = bboxes + (size_t)bi * 4;
    int x1 = max(bb[0], 0), y1 = max(bb[1], 0);
    int x2 = min(bb[2], WW), y2 = min(bb[3], HH);
    int w = x2 - x1, h = y2 - y1;
    if (w <= 0 || h <= 0) {
        if (threadIdx.x == 0) obj[bi] = 0.f;
        return;
    }
    const int wh = w * h;
    int tgt = (wh - 1) >> 1;            // lower median index
    const float* dbase = depth + (size_t)b * HH * WW;

    __shared__ unsigned int hist[256];
    __shared__ unsigned int sel_prefix, sel_target;
    unsigned int prefix = 0;

    for (int pass = 0; pass < 4; ++pass) {
        const int shift = 24 - 8 * pass;
        hist[threadIdx.x] = 0;
        __syncthreads();
        const unsigned int mask_high = (pass == 0) ? 0u : (0xFFFFFFFFu << (shift + 8));
        for (int idx = threadIdx.x; idx < wh; idx += 256) {
            int yy = y1 + idx / w, xx = x1 + idx % w;
            unsigned int uu = __float_as_uint(dbase[yy * WW + xx]);
            if ((uu & mask_high) == (prefix & mask_high))
                atomicAdd(&hist[(uu >> shift) & 255], 1u);
        }
        __syncthreads();
        if (threadIdx.x == 0) {
            unsigned int cum = 0;
            for (int bin = 0; bin < 256; ++bin) {
                unsigned int c = hist[bin];
                if (cum + c > (unsigned int)tgt) {
                    sel_target = (unsigned int)tgt - cum;
                    sel_prefix = prefix | ((unsigned int)bin << shift);
                    break;
                }
                cum += c;
            }
        }
        __syncthreads();
        prefix = sel_prefix;
        tgt = (int)sel_target;
    }
    if (threadIdx.x == 0) obj[bi] = __uint_as_float(prefix);
}

extern "C" void kernel_launch(void* const* d_in, const int* in_sizes, int n_in,
                              void* d_out, int out_size, void* d_ws, size_t ws_size,
                              hipStream_t stream) {
    const float* features = (const float*)d_in[0];
    const int*   bboxes   = (const int*)d_in[1];
    const float* w1  = (const float*)d_in[2];
    const float* b1  = (const float*)d_in[3];
    const float* g1  = (const float*)d_in[4];
    const float* be1 = (const float*)d_in[5];
    const float* m1  = (const float*)d_in[6];
    const float* v1  = (const float*)d_in[7];
    const float* w2  = (const float*)d_in[8];
    const float* b2  = (const float*)d_in[9];
    const float* g2  = (const float*)d_in[10];
    const float* be2 = (const float*)d_in[11];
    const float* m2  = (const float*)d_in[12];
    const float* v2  = (const float*)d_in[13];
    const float* w3  = (const float*)d_in[14];
    const float* b3  = (const float*)d_in[15];
    const float* uw1 = (const float*)d_in[16];
    const float* ub1 = (const float*)d_in[17];
    const float* uw2 = (const float*)d_in[18];
    const float* ub2 = (const float*)d_in[19];
    float* out = (float*)d_out;

    char* ws = (char*)d_ws;
    unsigned short* feat_t = (unsigned short*)(ws);                 // 62,914,560  (reused as h2_t)
    unsigned short* h1_t   = (unsigned short*)(ws + 62914560);      // 62,914,560
    unsigned short* u_t    = (unsigned short*)(ws + 125829120);     // 31,457,280
    unsigned short* w1T    = (unsigned short*)(ws + 157286400);     // 1,179,648
    unsigned short* w2T    = w1T + 589824;                          // 1,179,648
    unsigned short* uw1T   = w2T + 589824;                          //   589,824
    float* scale1 = (float*)(uw1T + 294912);
    float* bias1  = scale1 + 256;
    float* scale2 = bias1 + 256;
    float* bias2  = scale2 + 256;
    float* uscale = bias2 + 256;
    float* ubias  = uscale + 128;
    unsigned short* zp = (unsigned short*)(ubias + 128);            // 256 B zero page

    prep_scalars<<<1, 256, 0, stream>>>(b1, g1, be1, m1, v1, b2, g2, be2, m2, v2, ub1,
                                        scale1, bias1, scale2, bias2, uscale, ubias, zp);
    prep_weights<<<5760, 256, 0, stream>>>(w1, w2, uw1, w1T, w2T, uw1T);
    pack_features<<<dim3(WW / 32, CIN / 32, BATCH * HH), 256, 0, stream>>>(features, feat_t);

    conv3x3_mfma<<<dim3(NPIX / 128, 2), 256, 0, stream>>>(feat_t, w1T, scale1, bias1, h1_t, zp, 256);
    conv3x3_mfma<<<dim3(NPIX / 128, 1), 256, 0, stream>>>(feat_t, uw1T, uscale, ubias, u_t, zp, 128);
    unsigned short* h2_t = feat_t;
    conv3x3_mfma<<<dim3(NPIX / 128, 2), 256, 0, stream>>>(h1_t, w2T, scale2, bias2, h2_t, zp, 256);

    head_depth<<<NPIX / 64, 256, 0, stream>>>(h2_t, w3, b3, out);
    head_unc<<<NPIX / 64, 256, 0, stream>>>(u_t, uw2, ub2, out + NPIX);
    median_kernel<<<BATCH * 64, 256, 0, stream>>>(out, bboxes, out + 2 * NPIX);
}

// Round 5
// 688.212 us; speedup vs baseline: 1.4826x; 1.1612x over previous
//
#include <hip/hip_runtime.h>
#include <hip/hip_bf16.h>

#define HH 96
#define WW 160
#define BATCH 8
#define NPIX (BATCH*HH*WW)   // 122880
#define CIN 256
#define IMG (HH*WW)          // 15360
#define PW 162               // padded width
#define PH 98                // padded height
#define PR (PH*PW)           // 15876 padded rows per image
#define PTOT (BATCH*PR)      // 127008 padded rows total

typedef short bf16x8 __attribute__((ext_vector_type(8)));
typedef float f32x4 __attribute__((ext_vector_type(4)));

__device__ __forceinline__ unsigned short f2bf(float f) {
    unsigned int u = __float_as_uint(f);
    u = (u + 0x7fffu + ((u >> 16) & 1u)) >> 16;   // RNE
    return (unsigned short)u;
}

__device__ __forceinline__ void gload16(const void* g, void* l) {
    __builtin_amdgcn_global_load_lds(
        (const __attribute__((address_space(1))) void*)g,
        (__attribute__((address_space(3))) void*)l,
        16, 0, 0);
}

// ---------------- prep: BN fold ----------------
__global__ __launch_bounds__(256) void prep_scalars(
    const float* __restrict__ b1, const float* __restrict__ g1, const float* __restrict__ be1,
    const float* __restrict__ m1, const float* __restrict__ v1,
    const float* __restrict__ b2, const float* __restrict__ g2, const float* __restrict__ be2,
    const float* __restrict__ m2, const float* __restrict__ v2,
    const float* __restrict__ ub1,
    float* __restrict__ scale1, float* __restrict__ bias1,
    float* __restrict__ scale2, float* __restrict__ bias2,
    float* __restrict__ ubias)
{
    int t = threadIdx.x;
    float s1 = g1[t] * rsqrtf(v1[t] + 1e-5f);
    scale1[t] = s1;
    bias1[t]  = (b1[t] - m1[t]) * s1 + be1[t];
    float s2 = g2[t] * rsqrtf(v2[t] + 1e-5f);
    scale2[t] = s2;
    bias2[t]  = (b2[t] - m2[t]) * s2 + be2[t];
    if (t < 128) ubias[t] = ub1[t];
}

// ---------------- prep: pack weights OIHW f32 -> [cout][pos][cin] bf16 ----------------
__global__ __launch_bounds__(256) void prep_weights(
    const float* __restrict__ w1, const float* __restrict__ w2, const float* __restrict__ uw1,
    unsigned short* __restrict__ w1T, unsigned short* __restrict__ w2T, unsigned short* __restrict__ uw1T)
{
    const int S = 256 * 2304;       // 589824
    int i = blockIdx.x * 256 + threadIdx.x;
    if (i < S) {
        int co = i / 2304, r = i % 2304, pos = r >> 8, ci = r & 255;
        w1T[i] = f2bf(w1[(co * 256 + ci) * 9 + pos]);
    } else if (i < 2 * S) {
        int j = i - S;
        int co = j / 2304, r = j % 2304, pos = r >> 8, ci = r & 255;
        w2T[j] = f2bf(w2[(co * 256 + ci) * 9 + pos]);
    } else {
        int j = i - 2 * S;          // < 128*2304
        int co = j / 2304, r = j % 2304, pos = r >> 8, ci = r & 255;
        uw1T[j] = f2bf(uw1[(co * 256 + ci) * 9 + pos]);
    }
}

// ---------------- zero the pad rows of both padded buffers ----------------
// per image: top row (162) + bottom row (162) + 96 interior rows x {left,right} = 516 pad rows
__global__ __launch_bounds__(128) void zero_pads(
    unsigned int* __restrict__ featP, unsigned int* __restrict__ h1P)
{
    int bid = blockIdx.x;                 // 2 * 8 * 516 = 8256
    unsigned int* buf = (bid < 4128) ? featP : h1P;
    int k = (bid < 4128) ? bid : (bid - 4128);   // r4 bug: bid&4095 skipped 4096..4127
    int img = k / 516, i = k % 516;
    int py, px;
    if (i < PW)            { py = 0;      px = i; }
    else if (i < 2 * PW)   { py = PH - 1; px = i - PW; }
    else { int q = i - 2 * PW; py = 1 + (q >> 1); px = (q & 1) ? (PW - 1) : 0; }
    size_t row = (size_t)img * PR + (size_t)py * PW + px;
    buf[row * 128 + threadIdx.x] = 0;     // 512 B row of zeros
}

// ---------------- prep: NCHW f32 -> padded NHWC bf16 ----------------
__global__ __launch_bounds__(256) void pack_features(
    const float* __restrict__ f, unsigned short* __restrict__ ft)
{
    __shared__ float tile[32][33];
    int x0 = blockIdx.x * 32;       // W/32 = 5
    int c0 = blockIdx.y * 32;       // C/32 = 8
    int by = blockIdx.z;            // B*H = 768
    int b = by / HH, y = by % HH;
    int tx = threadIdx.x & 31, tg = threadIdx.x >> 5;   // tg 0..7
    const float* src = f + (((size_t)(b * CIN + c0) * HH + y) * WW) + x0;
    #pragma unroll
    for (int i = 0; i < 4; ++i) {
        int cl = tg + i * 8;
        tile[cl][tx] = src[(size_t)cl * HH * WW + tx];
    }
    __syncthreads();
    size_t rbase = (size_t)b * PR + (size_t)(y + 1) * PW + (x0 + 1);
    #pragma unroll
    for (int i = 0; i < 4; ++i) {
        int xl = tg + i * 8;
        ft[(rbase + xl) * 256 + c0 + tx] = f2bf(tile[tx][xl]);
    }
}

// ---------------- 3x3 conv, implicit GEMM, padded input, shared-dy B staging ----------------
// K loop = 8 cc-chunks x 3 dy. Per barrier-pair: stage 3 A pos-tiles (24 KB) + ONE
// 144-row B tile (9 KB) that serves all 3 dx shifts (dx = LDS row offset).
// 24 barrier pairs/block, 48 MFMA/wave per pair (was 72 pairs x 16).
// No boundary logic in the K loop: input is spatially zero-padded.
// Row-wrap: pixel j with x0+j>=WW lives at padded addr r0+j+(PW-WW) = r0+j+2.
// Swizzle (r3, verified conflict-free): lane l stages row l>>2, quarter (l&3)^((l>>3)&3);
// fragment at logical (row, quad) reads phys quarter quad^((row>>1)&3).
// mode: 0 = linear bf16 out [n][Cout]; 1 = padded bf16 out (256ch rows);
//       2 = fused uncertainty head (relu -> 1x1 uw2 dot -> softplus -> f32)
__global__ __launch_bounds__(256) void conv3x3_mfma(
    const unsigned short* __restrict__ inP,
    const unsigned short* __restrict__ wT,
    const float* __restrict__ scale, const float* __restrict__ bias,
    unsigned short* __restrict__ outT,
    float* __restrict__ uout,
    const float* __restrict__ uw2, const float* __restrict__ ub2,
    int Cout, int mode)
{
    __shared__ unsigned short Alds[3 * 128 * 32];   // 24576 B, [pos][slot][...]
    __shared__ unsigned short Blds[144 * 32];       // 9216 B
    __shared__ float usum[2][128];

    const int t = threadIdx.x;
    const int wave = t >> 6;
    const int l = t & 63;
    const int n0 = blockIdx.x * 128;
    const int m0 = blockIdx.y * 128;

    const int b0 = n0 / IMG;
    const int rem0 = n0 % IMG;
    const int y0 = rem0 / WW;
    const int x0 = rem0 % WW;
    const int r0 = b0 * PR + (y0 + 1) * PW + (x0 + 1);   // padded row of first output pixel

    const int lrow = l >> 2;
    const int lkq = (l & 3) ^ ((l >> 3) & 3);

    // A staging per-lane source bases (two 16-row slots per wave)
    const unsigned short* asrc0 = wT + (size_t)(m0 + wave * 32 + lrow) * 9 * 256 + lkq * 8;
    const unsigned short* asrc1 = asrc0 + (size_t)16 * 9 * 256;

    char* AldsB = (char*)Alds;
    char* BldsB = (char*)Blds;
    char* aldst = AldsB + wave * 2048;   // + dx*8192 (+1024 for second slot)

    const int wm = wave >> 1, wn = wave & 1;
    const int quad = l >> 4, lane16 = l & 15;
    const int aoff = lane16 * 64 + ((quad ^ ((lane16 >> 1) & 3)) << 4);

    // B fragment base tile-rows: pixel j -> r0 + j (+2 if wrapped) ; tile origin rs = r0
    // + (dyi-1)*PW - 8, dx shift adds 0..2; base = j + wrap + 7 (dx=0 means x-1 => -1+8=7)
    int browbase[4];
    #pragma unroll
    for (int i = 0; i < 4; ++i) {
        int j = wn * 64 + i * 16 + lane16;
        browbase[i] = j + ((x0 + j) >= WW ? 2 : 0) + 7;
    }

    f32x4 acc[4][4];
    #pragma unroll
    for (int mt = 0; mt < 4; ++mt)
        #pragma unroll
        for (int nt = 0; nt < 4; ++nt)
            acc[mt][nt] = (f32x4){0.f, 0.f, 0.f, 0.f};

    for (int cc = 0; cc < 8; ++cc) {
        const int ccoff = cc * 32;
        for (int dyi = 0; dyi < 3; ++dyi) {
            __syncthreads();
            // ---- stage A: 3 pos-tiles (pos = dyi*3 + dx), 6 instr/wave
            const unsigned short* a0 = asrc0 + (dyi * 3) * 256 + ccoff;
            const unsigned short* a1 = asrc1 + (dyi * 3) * 256 + ccoff;
            #pragma unroll
            for (int dxp = 0; dxp < 3; ++dxp) {
                gload16(a0 + dxp * 256, aldst + dxp * 8192);
                gload16(a1 + dxp * 256, aldst + dxp * 8192 + 1024);
            }
            // ---- stage B: 144 padded rows [r0 + (dyi-1)*PW - 8, +144), 9 slots
            const ptrdiff_t rs = (ptrdiff_t)r0 + (ptrdiff_t)(dyi - 1) * PW - 8;
            const unsigned short* bs = inP + (rs + lrow) * 256 + ccoff + lkq * 8
                                           + (size_t)wave * 8192;   // wave covers slots 2w,2w+1
            gload16(bs, BldsB + wave * 2048);
            gload16(bs + 4096, BldsB + wave * 2048 + 1024);
            if (wave == 3) gload16(bs + 8192, BldsB + 8192);        // slot 8
            __syncthreads();
            // ---- compute: 3 dx shifts x 16 MFMA
            #pragma unroll
            for (int dx = 0; dx < 3; ++dx) {
                bf16x8 af[4], bfr[4];
                #pragma unroll
                for (int mt = 0; mt < 4; ++mt)
                    af[mt] = *(const bf16x8*)(AldsB + dx * 8192 + ((wm * 4 + mt) << 10) + aoff);
                #pragma unroll
                for (int i = 0; i < 4; ++i) {
                    int row = browbase[i] + dx;
                    int ba = (row << 6) + ((quad ^ ((row >> 1) & 3)) << 4);
                    bfr[i] = *(const bf16x8*)(BldsB + ba);
                }
                #pragma unroll
                for (int mt = 0; mt < 4; ++mt)
                    #pragma unroll
                    for (int nt = 0; nt < 4; ++nt)
                        acc[mt][nt] = __builtin_amdgcn_mfma_f32_16x16x32_bf16(
                            af[mt], bfr[nt], acc[mt][nt], 0, 0, 0);
            }
        }
    }

    if (mode == 2) {
        // fused uncertainty head: relu(acc+bias) dot uw2 over all 128 channels -> softplus
        float s[4] = {0.f, 0.f, 0.f, 0.f};
        #pragma unroll
        for (int mt = 0; mt < 4; ++mt) {
            const int mg = wm * 64 + mt * 16 + quad * 4;
            const float4 bi = *(const float4*)&bias[mg];
            const float4 uw = *(const float4*)&uw2[mg];
            #pragma unroll
            for (int nt = 0; nt < 4; ++nt) {
                s[nt] += fmaxf(acc[mt][nt][0] + bi.x, 0.f) * uw.x
                       + fmaxf(acc[mt][nt][1] + bi.y, 0.f) * uw.y
                       + fmaxf(acc[mt][nt][2] + bi.z, 0.f) * uw.z
                       + fmaxf(acc[mt][nt][3] + bi.w, 0.f) * uw.w;
            }
        }
        #pragma unroll
        for (int nt = 0; nt < 4; ++nt) {
            s[nt] += __shfl_xor(s[nt], 16);
            s[nt] += __shfl_xor(s[nt], 32);
        }
        if (quad == 0) {
            #pragma unroll
            for (int nt = 0; nt < 4; ++nt)
                usum[wm][wn * 64 + nt * 16 + lane16] = s[nt];
        }
        __syncthreads();
        if (t < 128) {
            float x = usum[0][t] + usum[1][t] + ub2[0];
            uout[n0 + t] = fmaxf(x, 0.f) + log1pf(expf(-fabsf(x)));
        }
        return;
    }

    // modes 0/1: y = relu(acc*scale + bias) -> bf16
    size_t obase[4];
    #pragma unroll
    for (int nt = 0; nt < 4; ++nt) {
        int n = n0 + wn * 64 + nt * 16 + lane16;
        if (mode == 1) {
            int b = n / IMG, rem = n % IMG, yy = rem / WW, xx = rem % WW;
            obase[nt] = ((size_t)(b * PH + yy + 1) * PW + (xx + 1)) * 256;
        } else {
            obase[nt] = (size_t)n * Cout;
        }
    }
    #pragma unroll
    for (int mt = 0; mt < 4; ++mt) {
        const int mg = m0 + wm * 64 + mt * 16 + quad * 4;
        const float4 sc = *(const float4*)&scale[mg];
        const float4 bi = *(const float4*)&bias[mg];
        #pragma unroll
        for (int nt = 0; nt < 4; ++nt) {
            ushort4 pk;
            pk.x = f2bf(fmaxf(acc[mt][nt][0] * sc.x + bi.x, 0.f));
            pk.y = f2bf(fmaxf(acc[mt][nt][1] * sc.y + bi.y, 0.f));
            pk.z = f2bf(fmaxf(acc[mt][nt][2] * sc.z + bi.z, 0.f));
            pk.w = f2bf(fmaxf(acc[mt][nt][3] * sc.w + bi.w, 0.f));
            *(ushort4*)&outT[obase[nt] + mg] = pk;
        }
    }
}

// ---------------- depth head: 1x1 conv over 256ch + sigmoid + depth transform ----------------
__global__ __launch_bounds__(256) void head_depth(
    const unsigned short* __restrict__ h2, const float* __restrict__ w3,
    const float* __restrict__ b3, float* __restrict__ out)
{
    __shared__ float ws[256];
    ws[threadIdx.x] = w3[threadIdx.x];
    __syncthreads();
    const int pix = blockIdx.x * 64 + (threadIdx.x >> 2);
    const int q = threadIdx.x & 3;
    const unsigned short* p = h2 + (size_t)pix * 256 + q * 64;
    float s = 0.f;
    #pragma unroll
    for (int i = 0; i < 64; i += 8) {
        uint4 v = *(const uint4*)(p + i);
        const float* wq = &ws[q * 64 + i];
        s += __uint_as_float(v.x << 16) * wq[0];
        s += __uint_as_float(v.x & 0xffff0000u) * wq[1];
        s += __uint_as_float(v.y << 16) * wq[2];
        s += __uint_as_float(v.y & 0xffff0000u) * wq[3];
        s += __uint_as_float(v.z << 16) * wq[4];
        s += __uint_as_float(v.z & 0xffff0000u) * wq[5];
        s += __uint_as_float(v.w << 16) * wq[6];
        s += __uint_as_float(v.w & 0xffff0000u) * wq[7];
    }
    s += __shfl_xor(s, 1);
    s += __shfl_xor(s, 2);
    if (q == 0) {
        float x = s + b3[0];
        float sig = 1.f / (1.f + expf(-x));
        out[pix] = 1.f / (0.01f + 9.99f * sig);
    }
}

// ---------------- per-box lower-median via 4-pass radix select on float bits ----------------
__global__ __launch_bounds__(256) void median_kernel(
    const float* __restrict__ depth, const int* __restrict__ bboxes, float* __restrict__ obj)
{
    const int bi = blockIdx.x;          // b*64 + box
    const int b = bi >> 6;
    const int* bb = bboxes + (size_t)bi * 4;
    int x1 = max(bb[0], 0), y1 = max(bb[1], 0);
    int x2 = min(bb[2], WW), y2 = min(bb[3], HH);
    int w = x2 - x1, h = y2 - y1;
    if (w <= 0 || h <= 0) {
        if (threadIdx.x == 0) obj[bi] = 0.f;
        return;
    }
    const int wh = w * h;
    int tgt = (wh - 1) >> 1;            // lower median index
    const float* dbase = depth + (size_t)b * HH * WW;

    __shared__ unsigned int hist[256];
    __shared__ unsigned int sel_prefix, sel_target;
    unsigned int prefix = 0;

    for (int pass = 0; pass < 4; ++pass) {
        const int shift = 24 - 8 * pass;
        hist[threadIdx.x] = 0;
        __syncthreads();
        const unsigned int mask_high = (pass == 0) ? 0u : (0xFFFFFFFFu << (shift + 8));
        for (int idx = threadIdx.x; idx < wh; idx += 256) {
            int yy = y1 + idx / w, xx = x1 + idx % w;
            unsigned int uu = __float_as_uint(dbase[yy * WW + xx]);
            if ((uu & mask_high) == (prefix & mask_high))
                atomicAdd(&hist[(uu >> shift) & 255], 1u);
        }
        __syncthreads();
        if (threadIdx.x == 0) {
            unsigned int cum = 0;
            for (int bin = 0; bin < 256; ++bin) {
                unsigned int c = hist[bin];
                if (cum + c > (unsigned int)tgt) {
                    sel_target = (unsigned int)tgt - cum;
                    sel_prefix = prefix | ((unsigned int)bin << shift);
                    break;
                }
                cum += c;
            }
        }
        __syncthreads();
        prefix = sel_prefix;
        tgt = (int)sel_target;
    }
    if (threadIdx.x == 0) obj[bi] = __uint_as_float(prefix);
}

extern "C" void kernel_launch(void* const* d_in, const int* in_sizes, int n_in,
                              void* d_out, int out_size, void* d_ws, size_t ws_size,
                              hipStream_t stream) {
    const float* features = (const float*)d_in[0];
    const int*   bboxes   = (const int*)d_in[1];
    const float* w1  = (const float*)d_in[2];
    const float* b1  = (const float*)d_in[3];
    const float* g1  = (const float*)d_in[4];
    const float* be1 = (const float*)d_in[5];
    const float* m1  = (const float*)d_in[6];
    const float* v1  = (const float*)d_in[7];
    const float* w2  = (const float*)d_in[8];
    const float* b2  = (const float*)d_in[9];
    const float* g2  = (const float*)d_in[10];
    const float* be2 = (const float*)d_in[11];
    const float* m2  = (const float*)d_in[12];
    const float* v2  = (const float*)d_in[13];
    const float* w3  = (const float*)d_in[14];
    const float* b3  = (const float*)d_in[15];
    const float* uw1 = (const float*)d_in[16];
    const float* ub1 = (const float*)d_in[17];
    const float* uw2 = (const float*)d_in[18];
    const float* ub2 = (const float*)d_in[19];
    float* out = (float*)d_out;

    char* ws = (char*)d_ws;
    // layout (bytes). Padded buffers have 8 KB read-slack gaps on both sides
    // (conv staging over/under-reads up to ~8 rows = 4 KB of garbage, never consumed).
    unsigned short* featP = (unsigned short*)(ws + 8192);        // 127008*512 = 65,028,096 -> end 65,036,288
    unsigned short* h1P   = (unsigned short*)(ws + 65044480);    // end 130,072,576
    unsigned short* h2    = (unsigned short*)(ws + 8192);        // alias featP (dead after uconv1); 62,914,560
    unsigned short* w1T   = (unsigned short*)(ws + 130080768);   // 1,179,648
    unsigned short* w2T   = w1T + 589824;                        // 1,179,648
    unsigned short* uw1T  = w2T + 589824;                        //   589,824
    float* scale1 = (float*)(uw1T + 294912);
    float* bias1  = scale1 + 256;
    float* scale2 = bias1 + 256;
    float* bias2  = scale2 + 256;
    float* ubias  = bias2 + 256;                                 // 128

    prep_scalars<<<1, 256, 0, stream>>>(b1, g1, be1, m1, v1, b2, g2, be2, m2, v2, ub1,
                                        scale1, bias1, scale2, bias2, ubias);
    prep_weights<<<5760, 256, 0, stream>>>(w1, w2, uw1, w1T, w2T, uw1T);
    zero_pads<<<8256, 128, 0, stream>>>((unsigned int*)featP, (unsigned int*)h1P);
    pack_features<<<dim3(WW / 32, CIN / 32, BATCH * HH), 256, 0, stream>>>(features, featP);

    // conv1: featP -> h1P (padded out, BN+ReLU folded)
    conv3x3_mfma<<<dim3(NPIX / 128, 2), 256, 0, stream>>>(
        featP, w1T, scale1, bias1, h1P, nullptr, nullptr, nullptr, 256, 1);
    // uconv1 + uncertainty head fused: featP -> softplus(uw2 . relu(conv)) f32
    conv3x3_mfma<<<dim3(NPIX / 128, 1), 256, 0, stream>>>(
        featP, uw1T, scale1, ubias, nullptr, out + NPIX, uw2, ub2, 128, 2);
    // conv2: h1P -> h2 (linear out; featP now dead, h2 aliases it)
    conv3x3_mfma<<<dim3(NPIX / 128, 2), 256, 0, stream>>>(
        h1P, w2T, scale2, bias2, h2, nullptr, nullptr, nullptr, 256, 0);

    head_depth<<<NPIX / 64, 256, 0, stream>>>(h2, w3, b3, out);
    median_kernel<<<BATCH * 64, 256, 0, stream>>>(out, bboxes, out + 2 * NPIX);
}

// Round 6
// 655.057 us; speedup vs baseline: 1.5576x; 1.0506x over previous
//
#include <hip/hip_runtime.h>
#include <hip/hip_bf16.h>

#define HH 96
#define WW 160
#define BATCH 8
#define NPIX (BATCH*HH*WW)   // 122880
#define CIN 256
#define IMG (HH*WW)          // 15360
#define PW 162               // padded width
#define PH 98                // padded height
#define PR (PH*PW)           // 15876 padded rows per image
#define PTOT (BATCH*PR)      // 127008 padded rows total

typedef short bf16x8 __attribute__((ext_vector_type(8)));
typedef float f32x4 __attribute__((ext_vector_type(4)));

__device__ __forceinline__ unsigned short f2bf(float f) {
    unsigned int u = __float_as_uint(f);
    u = (u + 0x7fffu + ((u >> 16) & 1u)) >> 16;   // RNE
    return (unsigned short)u;
}

__device__ __forceinline__ void gload16(const void* g, void* l) {
    __builtin_amdgcn_global_load_lds(
        (const __attribute__((address_space(1))) void*)g,
        (__attribute__((address_space(3))) void*)l,
        16, 0, 0);
}

// ---------------- prep: BN fold ----------------
// scale1/bias1 are 384-entry combined arrays: [0,256) = conv1 BN fold, bias1[256..384) = ub1.
__global__ __launch_bounds__(256) void prep_scalars(
    const float* __restrict__ b1, const float* __restrict__ g1, const float* __restrict__ be1,
    const float* __restrict__ m1, const float* __restrict__ v1,
    const float* __restrict__ b2, const float* __restrict__ g2, const float* __restrict__ be2,
    const float* __restrict__ m2, const float* __restrict__ v2,
    const float* __restrict__ ub1,
    float* __restrict__ scale1, float* __restrict__ bias1,
    float* __restrict__ scale2, float* __restrict__ bias2)
{
    int t = threadIdx.x;
    float s1 = g1[t] * rsqrtf(v1[t] + 1e-5f);
    scale1[t] = s1;
    bias1[t]  = (b1[t] - m1[t]) * s1 + be1[t];
    float s2 = g2[t] * rsqrtf(v2[t] + 1e-5f);
    scale2[t] = s2;
    bias2[t]  = (b2[t] - m2[t]) * s2 + be2[t];
    if (t < 128) { scale1[256 + t] = 1.0f; bias1[256 + t] = ub1[t]; }
}

// ---------------- prep: pack weights OIHW f32 -> [cout][pos][cin] bf16 ----------------
__global__ __launch_bounds__(256) void prep_weights(
    const float* __restrict__ w1, const float* __restrict__ w2, const float* __restrict__ uw1,
    unsigned short* __restrict__ w1T, unsigned short* __restrict__ w2T, unsigned short* __restrict__ uw1T)
{
    const int S = 256 * 2304;       // 589824
    int i = blockIdx.x * 256 + threadIdx.x;
    if (i < S) {
        int co = i / 2304, r = i % 2304, pos = r >> 8, ci = r & 255;
        w1T[i] = f2bf(w1[(co * 256 + ci) * 9 + pos]);
    } else if (i < 2 * S) {
        int j = i - S;
        int co = j / 2304, r = j % 2304, pos = r >> 8, ci = r & 255;
        w2T[j] = f2bf(w2[(co * 256 + ci) * 9 + pos]);
    } else {
        int j = i - 2 * S;          // < 128*2304
        int co = j / 2304, r = j % 2304, pos = r >> 8, ci = r & 255;
        uw1T[j] = f2bf(uw1[(co * 256 + ci) * 9 + pos]);
    }
}

// ---------------- zero the pad rows of both padded buffers ----------------
__global__ __launch_bounds__(128) void zero_pads(
    unsigned int* __restrict__ featP, unsigned int* __restrict__ h1P)
{
    int bid = blockIdx.x;                 // 2 * 8 * 516 = 8256
    unsigned int* buf = (bid < 4128) ? featP : h1P;
    int k = (bid < 4128) ? bid : (bid - 4128);
    int img = k / 516, i = k % 516;
    int py, px;
    if (i < PW)            { py = 0;      px = i; }
    else if (i < 2 * PW)   { py = PH - 1; px = i - PW; }
    else { int q = i - 2 * PW; py = 1 + (q >> 1); px = (q & 1) ? (PW - 1) : 0; }
    size_t row = (size_t)img * PR + (size_t)py * PW + px;
    buf[row * 128 + threadIdx.x] = 0;     // 512 B row of zeros
}

// ---------------- prep: NCHW f32 -> padded NHWC bf16 ----------------
__global__ __launch_bounds__(256) void pack_features(
    const float* __restrict__ f, unsigned short* __restrict__ ft)
{
    __shared__ float tile[32][33];
    int x0 = blockIdx.x * 32;       // W/32 = 5
    int c0 = blockIdx.y * 32;       // C/32 = 8
    int by = blockIdx.z;            // B*H = 768
    int b = by / HH, y = by % HH;
    int tx = threadIdx.x & 31, tg = threadIdx.x >> 5;   // tg 0..7
    const float* src = f + (((size_t)(b * CIN + c0) * HH + y) * WW) + x0;
    #pragma unroll
    for (int i = 0; i < 4; ++i) {
        int cl = tg + i * 8;
        tile[cl][tx] = src[(size_t)cl * HH * WW + tx];
    }
    __syncthreads();
    size_t rbase = (size_t)b * PR + (size_t)(y + 1) * PW + (x0 + 1);
    #pragma unroll
    for (int i = 0; i < 4; ++i) {
        int xl = tg + i * 8;
        ft[(rbase + xl) * 256 + c0 + tx] = f2bf(tile[tx][xl]);
    }
}

// ---------------- 3x3 conv, implicit GEMM, padded input, shared-dy B staging ----------------
// XCD swizzle: l=(xcd,j); spatial s = xcd*120 + j/My, m-tile = j%My. 120 spatial
// blocks = exactly one image per XCD -> B dy-overlap + cross-m reuse hit that XCD's L2
// (per-cc working set ~1 MB vs 4 MB L2), instead of 3x HBM refetch (r5: FETCH=259MB=3x65).
// K loop = 8 cc-chunks x 3 dy; 24 barrier pairs, 48 MFMA/wave/pair.
// Row-wrap: pixel j with x0+j>=WW lives at padded addr r0+j+(PW-WW)=r0+j+2.
// Swizzle (r3, conflict-free): lane l stages row l>>2, quarter (l&3)^((l>>3)&3).
// mode 0: linear bf16 out (conv2), My=2.
// mode 1: merged conv1 (padded bf16 out, m0<256) + fused uncertainty head (m0==256:
//         relu(acc+bias[256+])·uw2 -> softplus -> f32), My=3, 384-row weights.
__global__ __launch_bounds__(256) void conv3x3_mfma(
    const unsigned short* __restrict__ inP,
    const unsigned short* __restrict__ wT,
    const float* __restrict__ scale, const float* __restrict__ bias,
    unsigned short* __restrict__ outT,
    float* __restrict__ uout,
    const float* __restrict__ uw2, const float* __restrict__ ub2,
    int Cout, int mode, int My)
{
    __shared__ unsigned short Alds[3 * 128 * 32];   // 24576 B, [pos][slot][...]
    __shared__ unsigned short Blds[144 * 32];       // 9216 B
    __shared__ float usum[2][128];

    const int t = threadIdx.x;
    const int wave = t >> 6;
    const int l = t & 63;

    const int lid = blockIdx.x;
    const int xcd = lid & 7;
    const int j = lid >> 3;
    const int n0 = (xcd * 120 + j / My) * 128;
    const int m0 = (j % My) * 128;
    const bool is_unc = (mode == 1) && (m0 == 256);

    const int b0 = n0 / IMG;
    const int rem0 = n0 % IMG;
    const int y0 = rem0 / WW;
    const int x0 = rem0 % WW;
    const int r0 = b0 * PR + (y0 + 1) * PW + (x0 + 1);   // padded row of first output pixel

    const int lrow = l >> 2;
    const int lkq = (l & 3) ^ ((l >> 3) & 3);

    // A staging per-lane source bases (two 16-row slots per wave)
    const unsigned short* asrc0 = wT + (size_t)(m0 + wave * 32 + lrow) * 9 * 256 + lkq * 8;
    const unsigned short* asrc1 = asrc0 + (size_t)16 * 9 * 256;

    char* AldsB = (char*)Alds;
    char* BldsB = (char*)Blds;
    char* aldst = AldsB + wave * 2048;   // + dx*8192 (+1024 for second slot)

    const int wm = wave >> 1, wn = wave & 1;
    const int quad = l >> 4, lane16 = l & 15;
    const int aoff = lane16 * 64 + ((quad ^ ((lane16 >> 1) & 3)) << 4);

    // B fragment base tile-rows: pixel j -> r0 + j (+2 if wrapped); staging origin
    // rs = r0 + (dyi-1)*PW - 8; dx adds 0..2; base = j + wrap + 7
    int browbase[4];
    #pragma unroll
    for (int i = 0; i < 4; ++i) {
        int jj = wn * 64 + i * 16 + lane16;
        browbase[i] = jj + ((x0 + jj) >= WW ? 2 : 0) + 7;
    }

    f32x4 acc[4][4];
    #pragma unroll
    for (int mt = 0; mt < 4; ++mt)
        #pragma unroll
        for (int nt = 0; nt < 4; ++nt)
            acc[mt][nt] = (f32x4){0.f, 0.f, 0.f, 0.f};

    for (int cc = 0; cc < 8; ++cc) {
        const int ccoff = cc * 32;
        for (int dyi = 0; dyi < 3; ++dyi) {
            __syncthreads();
            // ---- stage A: 3 pos-tiles (pos = dyi*3 + dx), 6 instr/wave
            const unsigned short* a0 = asrc0 + (dyi * 3) * 256 + ccoff;
            const unsigned short* a1 = asrc1 + (dyi * 3) * 256 + ccoff;
            #pragma unroll
            for (int dxp = 0; dxp < 3; ++dxp) {
                gload16(a0 + dxp * 256, aldst + dxp * 8192);
                gload16(a1 + dxp * 256, aldst + dxp * 8192 + 1024);
            }
            // ---- stage B: 144 padded rows [r0 + (dyi-1)*PW - 8, +144), 9 slots
            const ptrdiff_t rs = (ptrdiff_t)r0 + (ptrdiff_t)(dyi - 1) * PW - 8;
            const unsigned short* bs = inP + (rs + lrow) * 256 + ccoff + lkq * 8
                                           + (size_t)wave * 8192;   // wave covers slots 2w,2w+1
            gload16(bs, BldsB + wave * 2048);
            gload16(bs + 4096, BldsB + wave * 2048 + 1024);
            if (wave == 3) gload16(bs + 8192, BldsB + 8192);        // slot 8
            __syncthreads();
            // ---- compute: 3 dx shifts x 16 MFMA
            #pragma unroll
            for (int dx = 0; dx < 3; ++dx) {
                bf16x8 af[4], bfr[4];
                #pragma unroll
                for (int mt = 0; mt < 4; ++mt)
                    af[mt] = *(const bf16x8*)(AldsB + dx * 8192 + ((wm * 4 + mt) << 10) + aoff);
                #pragma unroll
                for (int i = 0; i < 4; ++i) {
                    int row = browbase[i] + dx;
                    int ba = (row << 6) + ((quad ^ ((row >> 1) & 3)) << 4);
                    bfr[i] = *(const bf16x8*)(BldsB + ba);
                }
                #pragma unroll
                for (int mt = 0; mt < 4; ++mt)
                    #pragma unroll
                    for (int nt = 0; nt < 4; ++nt)
                        acc[mt][nt] = __builtin_amdgcn_mfma_f32_16x16x32_bf16(
                            af[mt], bfr[nt], acc[mt][nt], 0, 0, 0);
            }
        }
    }

    if (is_unc) {
        // fused uncertainty head: relu(acc+ub1) dot uw2 over all 128 channels -> softplus
        const float* ub = bias + 256;
        float s[4] = {0.f, 0.f, 0.f, 0.f};
        #pragma unroll
        for (int mt = 0; mt < 4; ++mt) {
            const int mg = wm * 64 + mt * 16 + quad * 4;
            const float4 bi = *(const float4*)&ub[mg];
            const float4 uw = *(const float4*)&uw2[mg];
            #pragma unroll
            for (int nt = 0; nt < 4; ++nt) {
                s[nt] += fmaxf(acc[mt][nt][0] + bi.x, 0.f) * uw.x
                       + fmaxf(acc[mt][nt][1] + bi.y, 0.f) * uw.y
                       + fmaxf(acc[mt][nt][2] + bi.z, 0.f) * uw.z
                       + fmaxf(acc[mt][nt][3] + bi.w, 0.f) * uw.w;
            }
        }
        #pragma unroll
        for (int nt = 0; nt < 4; ++nt) {
            s[nt] += __shfl_xor(s[nt], 16);
            s[nt] += __shfl_xor(s[nt], 32);
        }
        if (quad == 0) {
            #pragma unroll
            for (int nt = 0; nt < 4; ++nt)
                usum[wm][wn * 64 + nt * 16 + lane16] = s[nt];
        }
        __syncthreads();
        if (t < 128) {
            float x = usum[0][t] + usum[1][t] + ub2[0];
            uout[n0 + t] = fmaxf(x, 0.f) + log1pf(expf(-fabsf(x)));
        }
        return;
    }

    // conv outputs: y = relu(acc*scale + bias) -> bf16 (mode1: padded rows; mode0: linear)
    size_t obase[4];
    #pragma unroll
    for (int nt = 0; nt < 4; ++nt) {
        int n = n0 + wn * 64 + nt * 16 + lane16;
        if (mode == 1) {
            int b = n / IMG, rem = n % IMG, yy = rem / WW, xx = rem % WW;
            obase[nt] = ((size_t)(b * PH + yy + 1) * PW + (xx + 1)) * 256;
        } else {
            obase[nt] = (size_t)n * Cout;
        }
    }
    #pragma unroll
    for (int mt = 0; mt < 4; ++mt) {
        const int mg = m0 + wm * 64 + mt * 16 + quad * 4;
        const float4 sc = *(const float4*)&scale[mg];
        const float4 bi = *(const float4*)&bias[mg];
        #pragma unroll
        for (int nt = 0; nt < 4; ++nt) {
            ushort4 pk;
            pk.x = f2bf(fmaxf(acc[mt][nt][0] * sc.x + bi.x, 0.f));
            pk.y = f2bf(fmaxf(acc[mt][nt][1] * sc.y + bi.y, 0.f));
            pk.z = f2bf(fmaxf(acc[mt][nt][2] * sc.z + bi.z, 0.f));
            pk.w = f2bf(fmaxf(acc[mt][nt][3] * sc.w + bi.w, 0.f));
            *(ushort4*)&outT[obase[nt] + mg] = pk;
        }
    }
}

// ---------------- depth head: 1x1 conv over 256ch + sigmoid + depth transform ----------------
__global__ __launch_bounds__(256) void head_depth(
    const unsigned short* __restrict__ h2, const float* __restrict__ w3,
    const float* __restrict__ b3, float* __restrict__ out)
{
    __shared__ float ws[256];
    ws[threadIdx.x] = w3[threadIdx.x];
    __syncthreads();
    const int pix = blockIdx.x * 64 + (threadIdx.x >> 2);
    const int q = threadIdx.x & 3;
    const unsigned short* p = h2 + (size_t)pix * 256 + q * 64;
    float s = 0.f;
    #pragma unroll
    for (int i = 0; i < 64; i += 8) {
        uint4 v = *(const uint4*)(p + i);
        const float* wq = &ws[q * 64 + i];
        s += __uint_as_float(v.x << 16) * wq[0];
        s += __uint_as_float(v.x & 0xffff0000u) * wq[1];
        s += __uint_as_float(v.y << 16) * wq[2];
        s += __uint_as_float(v.y & 0xffff0000u) * wq[3];
        s += __uint_as_float(v.z << 16) * wq[4];
        s += __uint_as_float(v.z & 0xffff0000u) * wq[5];
        s += __uint_as_float(v.w << 16) * wq[6];
        s += __uint_as_float(v.w & 0xffff0000u) * wq[7];
    }
    s += __shfl_xor(s, 1);
    s += __shfl_xor(s, 2);
    if (q == 0) {
        float x = s + b3[0];
        float sig = 1.f / (1.f + expf(-x));
        out[pix] = 1.f / (0.01f + 9.99f * sig);
    }
}

// ---------------- per-box lower-median via 4-pass radix select on float bits ----------------
__global__ __launch_bounds__(256) void median_kernel(
    const float* __restrict__ depth, const int* __restrict__ bboxes, float* __restrict__ obj)
{
    const int bi = blockIdx.x;          // b*64 + box
    const int b = bi >> 6;
    const int* bb = bboxes + (size_t)bi * 4;
    int x1 = max(bb[0], 0), y1 = max(bb[1], 0);
    int x2 = min(bb[2], WW), y2 = min(bb[3], HH);
    int w = x2 - x1, h = y2 - y1;
    if (w <= 0 || h <= 0) {
        if (threadIdx.x == 0) obj[bi] = 0.f;
        return;
    }
    const int wh = w * h;
    int tgt = (wh - 1) >> 1;            // lower median index
    const float* dbase = depth + (size_t)b * HH * WW;

    __shared__ unsigned int hist[256];
    __shared__ unsigned int sel_prefix, sel_target;
    unsigned int prefix = 0;

    for (int pass = 0; pass < 4; ++pass) {
        const int shift = 24 - 8 * pass;
        hist[threadIdx.x] = 0;
        __syncthreads();
        const unsigned int mask_high = (pass == 0) ? 0u : (0xFFFFFFFFu << (shift + 8));
        for (int idx = threadIdx.x; idx < wh; idx += 256) {
            int yy = y1 + idx / w, xx = x1 + idx % w;
            unsigned int uu = __float_as_uint(dbase[yy * WW + xx]);
            if ((uu & mask_high) == (prefix & mask_high))
                atomicAdd(&hist[(uu >> shift) & 255], 1u);
        }
        __syncthreads();
        if (threadIdx.x == 0) {
            unsigned int cum = 0;
            for (int bin = 0; bin < 256; ++bin) {
                unsigned int c = hist[bin];
                if (cum + c > (unsigned int)tgt) {
                    sel_target = (unsigned int)tgt - cum;
                    sel_prefix = prefix | ((unsigned int)bin << shift);
                    break;
                }
                cum += c;
            }
        }
        __syncthreads();
        prefix = sel_prefix;
        tgt = (int)sel_target;
    }
    if (threadIdx.x == 0) obj[bi] = __uint_as_float(prefix);
}

extern "C" void kernel_launch(void* const* d_in, const int* in_sizes, int n_in,
                              void* d_out, int out_size, void* d_ws, size_t ws_size,
                              hipStream_t stream) {
    const float* features = (const float*)d_in[0];
    const int*   bboxes   = (const int*)d_in[1];
    const float* w1  = (const float*)d_in[2];
    const float* b1  = (const float*)d_in[3];
    const float* g1  = (const float*)d_in[4];
    const float* be1 = (const float*)d_in[5];
    const float* m1  = (const float*)d_in[6];
    const float* v1  = (const float*)d_in[7];
    const float* w2  = (const float*)d_in[8];
    const float* b2  = (const float*)d_in[9];
    const float* g2  = (const float*)d_in[10];
    const float* be2 = (const float*)d_in[11];
    const float* m2  = (const float*)d_in[12];
    const float* v2  = (const float*)d_in[13];
    const float* w3  = (const float*)d_in[14];
    const float* b3  = (const float*)d_in[15];
    const float* uw1 = (const float*)d_in[16];
    const float* ub1 = (const float*)d_in[17];
    const float* uw2 = (const float*)d_in[18];
    const float* ub2 = (const float*)d_in[19];
    float* out = (float*)d_out;

    char* ws = (char*)d_ws;
    // layout (bytes). Padded buffers have 8 KB read-slack gaps on both sides.
    unsigned short* featP = (unsigned short*)(ws + 8192);        // 65,028,096 -> end 65,036,288
    unsigned short* h1P   = (unsigned short*)(ws + 65044480);    // end 130,072,576
    unsigned short* h2    = (unsigned short*)(ws + 8192);        // alias featP (dead after conv1 pass)
    unsigned short* w1T   = (unsigned short*)(ws + 130080768);   // 256 rows, 1,179,648 B
    unsigned short* uw1T  = w1T + 256 * 2304;                    // 128 rows right after -> combined 384
    unsigned short* w2T   = uw1T + 128 * 2304;                   // 1,179,648 B
    float* scale1 = (float*)(w2T + 589824);                      // 384
    float* bias1  = scale1 + 384;                                // 384 (256 BN-fold + 128 ub1)
    float* scale2 = bias1 + 384;                                 // 256
    float* bias2  = scale2 + 256;                                // 256

    prep_scalars<<<1, 256, 0, stream>>>(b1, g1, be1, m1, v1, b2, g2, be2, m2, v2, ub1,
                                        scale1, bias1, scale2, bias2);
    prep_weights<<<5760, 256, 0, stream>>>(w1, w2, uw1, w1T, w2T, uw1T);
    zero_pads<<<8256, 128, 0, stream>>>((unsigned int*)featP, (unsigned int*)h1P);
    pack_features<<<dim3(WW / 32, CIN / 32, BATCH * HH), 256, 0, stream>>>(features, featP);

    // merged conv1 (BN+ReLU, padded out) + fused uncertainty head; My=3, 2880 blocks
    conv3x3_mfma<<<2880, 256, 0, stream>>>(
        featP, w1T, scale1, bias1, h1P, out + NPIX, uw2, ub2, 256, 1, 3);
    // conv2: h1P -> h2 (linear out; featP dead, h2 aliases it); My=2, 1920 blocks
    conv3x3_mfma<<<1920, 256, 0, stream>>>(
        h1P, w2T, scale2, bias2, h2, nullptr, nullptr, nullptr, 256, 0, 2);

    head_depth<<<NPIX / 64, 256, 0, stream>>>(h2, w3, b3, out);
    median_kernel<<<BATCH * 64, 256, 0, stream>>>(out, bboxes, out + 2 * NPIX);
}